// Round 4
// baseline (176.978 us; speedup 1.0000x reference)
//
#include <hip/hip_runtime.h>
#include <cstdint>
#include <cstddef>

// x[64][1024][32] f32, W[1024][32] f32, b[1024] f32 -> out[64][1024][1024] f32
#define BATCH   64
#define SEQLEN  1024
#define KDIM    32
#define ODIM    1024
#define NTOK    (BATCH * SEQLEN)

typedef __attribute__((ext_vector_type(8))) short bf16x8;   // 8 bf16 = 4 VGPRs
typedef __attribute__((ext_vector_type(4))) float f32x4;

// exact f32 -> bf16 truncation; exact for integer-valued f32 |v| <= 255 and {-1,0,1}
__device__ __forceinline__ unsigned short f32_to_bf16_exact(float f) {
    union { float f; unsigned int u; } cv; cv.f = f;
    return (unsigned short)(cv.u >> 16);
}

// ---------------------------------------------------------------------------
// Kernel 1: W |.| partial sums. 8 blocks x 256 threads x 16 contiguous elems.
// ---------------------------------------------------------------------------
__global__ __launch_bounds__(256) void wpartial_kernel(const float* __restrict__ W,
                                                       float* __restrict__ partial) {
    __shared__ float red[256];
    const int t = threadIdx.x;
    const float4* W4 = reinterpret_cast<const float4*>(W) + (size_t)blockIdx.x * 1024 + t * 4;
    float acc = 0.f;
    #pragma unroll
    for (int j = 0; j < 4; ++j) {
        float4 v = W4[j];
        acc += fabsf(v.x) + fabsf(v.y) + fabsf(v.z) + fabsf(v.w);
    }
    red[t] = acc;
    __syncthreads();
    for (int step = 128; step > 0; step >>= 1) {
        if (t < step) red[t] += red[t + step];
        __syncthreads();
    }
    if (t == 0) partial[blockIdx.x] = red[0];
}

// ---------------------------------------------------------------------------
// Kernel 2: fused BitLinear, contiguous-store edition.
// Block = one batch b x 16 consecutive s x ALL 1024 o  -> one contiguous
// 64 KB output region per block (matches the 6.9 TB/s fill pattern).
// 4 waves, wave wid owns o in [wid*256, wid*256+256) = 16 MFMA fragments.
// Accumulator layout (D col=token=lane&15, row=o=(lane>>4)*4+reg) is
// transposed through a 64 KB XOR-swizzled LDS tile; store loop then writes
// 16 x 4 KB fully-contiguous dwordx4 streams.
// ---------------------------------------------------------------------------
__global__ __launch_bounds__(256) void bitgemm_fused(
    const float* __restrict__ x,        // [65536][32]
    const float* __restrict__ W,        // [1024][32]
    const float* __restrict__ bias,     // [1024]
    const float* __restrict__ partial,  // [8]
    float* __restrict__ out)            // [65536][1024]
{
    __shared__ float lds[16 * 1024];    // 64 KB: 16 token-rows x 1024 o (swizzled)

    const int t    = threadIdx.x;
    const int lane = t & 63;
    const int wid  = t >> 6;
    const int l15  = lane & 15;
    const int hi   = lane >> 4;              // 0..3 (k-slice / o-subrow)

    const int b    = blockIdx.x >> 6;        // 0..63
    const int s0   = (blockIdx.x & 63) << 4; // 0,16,..,1008
    const int tok0 = (b << 10) + s0;
    const int oq   = wid << 8;               // wave's o-base (0/256/512/768)

    // ---- weight scale from the 8 partials (uniform scalar path) ----
    float tot = 0.f;
    #pragma unroll
    for (int p = 0; p < 8; ++p) tot += partial[p];
    const float rw = fmaxf(tot * (1.0f / 32768.0f), 1e-5f);  // 1/scale_w
    const float sc = 1.0f / rw;                              // scale_w

    // ---- activation quant, ONCE per block (wave reads contiguous 2 KB) ----
    const float* xr = x + (size_t)(tok0 + l15) * KDIM + hi * 8;
    float4 xa = *reinterpret_cast<const float4*>(xr);
    float4 xb = *reinterpret_cast<const float4*>(xr + 4);
    float am = fmaxf(fmaxf(fmaxf(fabsf(xa.x), fabsf(xa.y)),
                           fmaxf(fabsf(xa.z), fabsf(xa.w))),
                     fmaxf(fmaxf(fabsf(xb.x), fabsf(xb.y)),
                           fmaxf(fabsf(xb.z), fabsf(xb.w))));
    am = fmaxf(am, __shfl_xor(am, 16));      // lanes {l15,+16,+32,+48} = one token
    am = fmaxf(am, __shfl_xor(am, 32));
    am = fmaxf(am, 1e-5f);
    const float xscale = 127.0f / am;        // |v*scale| <= 127: clip can't bind
    union { bf16x8 v; unsigned short s[8]; } bu;
    {
        float e[8] = {xa.x, xa.y, xa.z, xa.w, xb.x, xb.y, xb.z, xb.w};
        #pragma unroll
        for (int j = 0; j < 8; ++j)
            bu.s[j] = f32_to_bf16_exact(rintf(e[j] * xscale)); // int in [-127,127]
    }
    const float rxw = am * (1.0f / 127.0f) * rw;   // combined 1/scales, per token

    // ---- A fragments: ternary-quantize W in-register (16 frags = 256 o) ----
    bf16x8 afrag[16];
    #pragma unroll
    for (int f = 0; f < 16; ++f) {
        const float* wr = W + (size_t)(oq + f * 16 + l15) * KDIM + hi * 8;
        float4 wa = *reinterpret_cast<const float4*>(wr);
        float4 wb = *reinterpret_cast<const float4*>(wr + 4);
        float e[8] = {wa.x, wa.y, wa.z, wa.w, wb.x, wb.y, wb.z, wb.w};
        union { bf16x8 v; unsigned short s[8]; } u;
        #pragma unroll
        for (int j = 0; j < 8; ++j)
            u.s[j] = f32_to_bf16_exact(fminf(fmaxf(rintf(e[j] * sc), -1.0f), 1.0f));
        afrag[f] = u.v;
    }

    // ---- 16 independent MFMAs ----
    f32x4 acc[16];
    #pragma unroll
    for (int f = 0; f < 16; ++f) {
        acc[f] = (f32x4){0.f, 0.f, 0.f, 0.f};
        acc[f] = __builtin_amdgcn_mfma_f32_16x16x32_bf16(afrag[f], bu.v, acc[f], 0, 0, 0);
    }

    // ---- epilogue: scale + bias + in-register f32 PE -> swizzled LDS ----
    // pe(s,o) = sin/cos(s * 10000^(-(o&~1)/1024)); f32 err << 7.2e-2 threshold.
    const float C  = -0.012976281620653759f;  // -log2(10000)/1024
    const float sf = (float)(s0 + l15);
    #pragma unroll
    for (int f = 0; f < 16; ++f) {
        const int oe = oq + f * 16 + hi * 4;              // multiple of 4
        f32x4 bv = *reinterpret_cast<const f32x4*>(bias + oe);
        float a0 = sf * exp2f(C * (float)oe);
        float a1 = sf * exp2f(C * (float)(oe + 2));
        f32x4 r;
        r[0] = fmaf(acc[f][0], rxw, bv[0] + sinf(a0));
        r[1] = fmaf(acc[f][1], rxw, bv[1] + cosf(a0));
        r[2] = fmaf(acc[f][2], rxw, bv[2] + sinf(a1));
        r[3] = fmaf(acc[f][3], rxw, bv[3] + cosf(a1));
        // logical (row = token l15, 16B-granule g = oe/4); physical g ^= (row&7)
        const int g = (oq >> 2) + f * 4 + hi;
        *reinterpret_cast<f32x4*>(&lds[(l15 << 10) + ((g ^ (l15 & 7)) << 2)]) = r;
    }

    __syncthreads();

    // ---- store: 16 iterations x 4 KB fully contiguous per block ----
    float* ob = out + (size_t)tok0 * ODIM;
    #pragma unroll
    for (int c = 0; c < 16; ++c) {
        f32x4 v = *reinterpret_cast<const f32x4*>(
            &lds[(c << 10) + (((t ^ (c & 7)) & 255) << 2)]);
        *reinterpret_cast<f32x4*>(ob + (c << 10) + (t << 2)) = v;
    }
}

// ---------------------------------------------------------------------------
extern "C" void kernel_launch(void* const* d_in, const int* in_sizes, int n_in,
                              void* d_out, int out_size, void* d_ws, size_t ws_size,
                              hipStream_t stream) {
    const float* x = (const float*)d_in[0];   // [64][1024][32]
    const float* W = (const float*)d_in[1];   // [1024][32]
    const float* b = (const float*)d_in[2];   // [1024]
    float* out = (float*)d_out;

    float* partial = (float*)d_ws;            // 8 floats

    wpartial_kernel<<<8, 256, 0, stream>>>(W, partial);
    bitgemm_fused<<<NTOK / 16, 256, 0, stream>>>(x, W, b, partial, out);
}

// Round 5
// 113.383 us; speedup vs baseline: 1.5609x; 1.5609x over previous
//
#include <hip/hip_runtime.h>
#include <cstdint>
#include <cstddef>

// x[64][1024][32] f32, W[1024][32] f32, b[1024] f32 -> out[64][1024][1024] f32
#define BATCH   64
#define SEQLEN  1024
#define KDIM    32
#define ODIM    1024
#define NTOK    (BATCH * SEQLEN)

typedef __attribute__((ext_vector_type(8))) short bf16x8;   // 8 bf16 = 4 VGPRs
typedef __attribute__((ext_vector_type(4))) float f32x4;

// exact f32 -> bf16 truncation; exact for integer-valued f32 |v| <= 255 and {-1,0,1}
__device__ __forceinline__ unsigned short f32_to_bf16_exact(float f) {
    union { float f; unsigned int u; } cv; cv.f = f;
    return (unsigned short)(cv.u >> 16);
}

// ---------------------------------------------------------------------------
// Kernel 1: W |.| partial sums. 8 blocks x 256 threads x 16 contiguous elems.
// ---------------------------------------------------------------------------
__global__ __launch_bounds__(256) void wpartial_kernel(const float* __restrict__ W,
                                                       float* __restrict__ partial) {
    __shared__ float red[256];
    const int t = threadIdx.x;
    const float4* W4 = reinterpret_cast<const float4*>(W) + (size_t)blockIdx.x * 1024 + t * 4;
    float acc = 0.f;
    #pragma unroll
    for (int j = 0; j < 4; ++j) {
        float4 v = W4[j];
        acc += fabsf(v.x) + fabsf(v.y) + fabsf(v.z) + fabsf(v.w);
    }
    red[t] = acc;
    __syncthreads();
    for (int step = 128; step > 0; step >>= 1) {
        if (t < step) red[t] += red[t + step];
        __syncthreads();
    }
    if (t == 0) partial[blockIdx.x] = red[0];
}

// ---------------------------------------------------------------------------
// Kernel 2: fused BitLinear, contiguous-store edition (spill-free).
// Block = one batch b x 16 consecutive s x ALL 1024 o -> one contiguous 64 KB
// output region. 4 waves; wave wid owns o in [wid*256, +256) = 16 fragments,
// processed ONE AT A TIME (quant -> MFMA -> epilogue -> LDS) to keep liveness
// ~30 regs. LDS is capacity-limiting (2 blocks/CU = 2 waves/SIMD), so
// __launch_bounds__(256,2) frees the allocator up to 256 VGPRs: no scratch.
// ---------------------------------------------------------------------------
__global__ __launch_bounds__(256, 2) void bitgemm_fused(
    const float* __restrict__ x,        // [65536][32]
    const float* __restrict__ W,        // [1024][32]
    const float* __restrict__ bias,     // [1024]
    const float* __restrict__ partial,  // [8]
    float* __restrict__ out)            // [65536][1024]
{
    __shared__ float lds[16 * 1024];    // 64 KB: 16 token-rows x 1024 o (swizzled)

    const int t    = threadIdx.x;
    const int lane = t & 63;
    const int wid  = t >> 6;
    const int l15  = lane & 15;
    const int hi   = lane >> 4;              // 0..3 (k-slice / o-subrow)

    const int b    = blockIdx.x >> 6;        // 0..63
    const int s0   = (blockIdx.x & 63) << 4; // 0,16,..,1008
    const int tok0 = (b << 10) + s0;
    const int oq   = wid << 8;               // wave's o-base (0/256/512/768)

    // ---- x load first (longest-latency independent load) ----
    const float* xr = x + (size_t)(tok0 + l15) * KDIM + hi * 8;
    float4 xa = *reinterpret_cast<const float4*>(xr);
    float4 xb = *reinterpret_cast<const float4*>(xr + 4);

    // ---- weight scale from the 8 partials (uniform scalar path) ----
    float tot = 0.f;
    #pragma unroll
    for (int p = 0; p < 8; ++p) tot += partial[p];
    const float rw = fmaxf(tot * (1.0f / 32768.0f), 1e-5f);  // 1/scale_w
    const float sc = 1.0f / rw;                              // scale_w

    // ---- activation quant (lanes {l15,+16,+32,+48} hold one token) ----
    float am = fmaxf(fmaxf(fmaxf(fabsf(xa.x), fabsf(xa.y)),
                           fmaxf(fabsf(xa.z), fabsf(xa.w))),
                     fmaxf(fmaxf(fabsf(xb.x), fabsf(xb.y)),
                           fmaxf(fabsf(xb.z), fabsf(xb.w))));
    am = fmaxf(am, __shfl_xor(am, 16));
    am = fmaxf(am, __shfl_xor(am, 32));
    am = fmaxf(am, 1e-5f);
    const float xscale = 127.0f / am;        // |v*scale| <= 127: clip can't bind
    union { bf16x8 v; unsigned short s[8]; } bu;
    {
        float e[8] = {xa.x, xa.y, xa.z, xa.w, xb.x, xb.y, xb.z, xb.w};
        #pragma unroll
        for (int j = 0; j < 8; ++j)
            bu.s[j] = f32_to_bf16_exact(rintf(e[j] * xscale)); // int in [-127,127]
    }
    const float rxw = am * (1.0f / 127.0f) * rw;   // combined 1/scales, per token

    // ---- per-fragment: W-quant -> MFMA -> bias+PE epilogue -> LDS ----
    const float C  = -0.012976281620653759f;  // -log2(10000)/1024
    const float sf = (float)(s0 + l15);
    #pragma unroll
    for (int f = 0; f < 16; ++f) {
        const float* wr = W + (size_t)(oq + f * 16 + l15) * KDIM + hi * 8;
        float4 wa = *reinterpret_cast<const float4*>(wr);
        float4 wb = *reinterpret_cast<const float4*>(wr + 4);
        union { bf16x8 v; unsigned short s[8]; } u;
        {
            float e[8] = {wa.x, wa.y, wa.z, wa.w, wb.x, wb.y, wb.z, wb.w};
            #pragma unroll
            for (int j = 0; j < 8; ++j)
                u.s[j] = f32_to_bf16_exact(fminf(fmaxf(rintf(e[j] * sc), -1.0f), 1.0f));
        }

        f32x4 acc = (f32x4){0.f, 0.f, 0.f, 0.f};
        acc = __builtin_amdgcn_mfma_f32_16x16x32_bf16(u.v, bu.v, acc, 0, 0, 0);

        const int oe = oq + f * 16 + hi * 4;              // multiple of 4
        f32x4 bv = *reinterpret_cast<const f32x4*>(bias + oe);
        float a0 = sf * exp2f(C * (float)oe);
        float a1 = sf * exp2f(C * (float)(oe + 2));
        f32x4 r;
        r[0] = fmaf(acc[0], rxw, bv[0] + sinf(a0));
        r[1] = fmaf(acc[1], rxw, bv[1] + cosf(a0));
        r[2] = fmaf(acc[2], rxw, bv[2] + sinf(a1));
        r[3] = fmaf(acc[3], rxw, bv[3] + cosf(a1));
        // logical (row = token l15, 16B-granule g); physical g ^= (row&7)
        const int g = (oq >> 2) + f * 4 + hi;
        *reinterpret_cast<f32x4*>(&lds[(l15 << 10) + ((g ^ (l15 & 7)) << 2)]) = r;
    }

    __syncthreads();

    // ---- store: 16 iterations x 4 KB fully contiguous per block ----
    float* ob = out + (size_t)tok0 * ODIM;
    #pragma unroll
    for (int c = 0; c < 16; ++c) {
        f32x4 v = *reinterpret_cast<const f32x4*>(
            &lds[(c << 10) + (((t ^ (c & 7)) & 255) << 2)]);
        *reinterpret_cast<f32x4*>(ob + (c << 10) + (t << 2)) = v;
    }
}

// ---------------------------------------------------------------------------
extern "C" void kernel_launch(void* const* d_in, const int* in_sizes, int n_in,
                              void* d_out, int out_size, void* d_ws, size_t ws_size,
                              hipStream_t stream) {
    const float* x = (const float*)d_in[0];   // [64][1024][32]
    const float* W = (const float*)d_in[1];   // [1024][32]
    const float* b = (const float*)d_in[2];   // [1024]
    float* out = (float*)d_out;

    float* partial = (float*)d_ws;            // 8 floats

    wpartial_kernel<<<8, 256, 0, stream>>>(W, partial);
    bitgemm_fused<<<NTOK / 16, 256, 0, stream>>>(x, W, b, partial, out);
}

// Round 6
// 91.989 us; speedup vs baseline: 1.9239x; 1.2326x over previous
//
#include <hip/hip_runtime.h>
#include <cstdint>
#include <cstddef>

// x[64][1024][32] f32, W[1024][32] f32, b[1024] f32 -> out[64][1024][1024] f32
#define BATCH   64
#define SEQLEN  1024
#define KDIM    32
#define ODIM    1024
#define NTOK    (BATCH * SEQLEN)

typedef __attribute__((ext_vector_type(8))) short bf16x8;   // 8 bf16 = 4 VGPRs
typedef __attribute__((ext_vector_type(4))) float f32x4;

// exact f32 -> bf16 truncation; exact for integer-valued f32 |v| <= 255 and {-1,0,1}
__device__ __forceinline__ unsigned short f32_to_bf16_exact(float f) {
    union { float f; unsigned int u; } cv; cv.f = f;
    return (unsigned short)(cv.u >> 16);
}

// ---------------------------------------------------------------------------
// Kernel 1: W |.| partial sums. 8 blocks x 256 threads x 16 contiguous elems.
// ---------------------------------------------------------------------------
__global__ __launch_bounds__(256) void wpartial_kernel(const float* __restrict__ W,
                                                       float* __restrict__ partial) {
    __shared__ float red[256];
    const int t = threadIdx.x;
    const float4* W4 = reinterpret_cast<const float4*>(W) + (size_t)blockIdx.x * 1024 + t * 4;
    float acc = 0.f;
    #pragma unroll
    for (int j = 0; j < 4; ++j) {
        float4 v = W4[j];
        acc += fabsf(v.x) + fabsf(v.y) + fabsf(v.z) + fabsf(v.w);
    }
    red[t] = acc;
    __syncthreads();
    for (int step = 128; step > 0; step >>= 1) {
        if (t < step) red[t] += red[t + step];
        __syncthreads();
    }
    if (t == 0) partial[blockIdx.x] = red[0];
}

// ---------------------------------------------------------------------------
// Kernel 2: ternary-quantize W -> wq bf16[o][k] ({-1,0,1}); 1 row/thread.
// ---------------------------------------------------------------------------
__global__ __launch_bounds__(256) void wquant_kernel(const float* __restrict__ W,
                                                     const float* __restrict__ partial,
                                                     unsigned short* __restrict__ wq) {
    const int o = blockIdx.x * 256 + threadIdx.x;      // 4 blocks x 256 = 1024 rows
    float tot = 0.f;
    #pragma unroll
    for (int p = 0; p < 8; ++p) tot += partial[p];
    const float sc = 1.0f / fmaxf(tot * (1.0f / 32768.0f), 1e-5f);

    const float4* wr = reinterpret_cast<const float4*>(W + (size_t)o * KDIM);
    unsigned short* row = wq + (size_t)o * KDIM;
    #pragma unroll
    for (int j = 0; j < 8; ++j) {
        float4 v = wr[j];
        float e[4] = {v.x, v.y, v.z, v.w};
        union { ushort4 u4; unsigned short s[4]; } u;
        #pragma unroll
        for (int c = 0; c < 4; ++c)
            u.s[c] = f32_to_bf16_exact(fminf(fmaxf(rintf(e[c] * sc), -1.0f), 1.0f));
        *reinterpret_cast<ushort4*>(row + j * 4) = u.u4;
    }
}

// ---------------------------------------------------------------------------
// Kernel 3: add-table add[s][o] = bias[o] + pe(s,o), f32, 4 MB.
// pe = sin/cos(s * 10000^(-(o&~1)/1024)); f32 err << 7.2e-2 threshold
// (rounds 3-5 empirically: absmax unchanged at 0.015625 with f32 PE).
// ---------------------------------------------------------------------------
__global__ __launch_bounds__(256) void pe_bias_kernel(const float* __restrict__ bias,
                                                      float* __restrict__ add) {
    const int g  = blockIdx.x * 256 + threadIdx.x;     // 16B granule index
    const int oe = (g << 2) & (ODIM - 1);              // multiple of 4
    const int s  = g >> 8;
    const float C = -0.012976281620653759f;            // -log2(10000)/1024
    const float sf = (float)s;
    float a0 = sf * exp2f(C * (float)oe);
    float a1 = sf * exp2f(C * (float)(oe + 2));
    f32x4 bv = *reinterpret_cast<const f32x4*>(bias + oe);
    f32x4 r;
    r[0] = bv[0] + sinf(a0);
    r[1] = bv[1] + cosf(a0);
    r[2] = bv[2] + sinf(a1);
    r[3] = bv[3] + cosf(a1);
    *reinterpret_cast<f32x4*>(add + ((size_t)g << 2)) = r;
}

// ---------------------------------------------------------------------------
// Kernel 4: BitLinear GEMM, contiguous-store, VALU-lean.
// Block = (s-chunk of 16, batch b) x ALL 1024 o -> one contiguous 64 KB output
// region. blockIdx: b = low 6 bits (so co-resident blocks share the same
// add-table rows -> L2-hot). 4 waves; wave wid owns o [wid*256,+256) = 16
// frags. D-layout transpose via XOR-swizzled LDS is INTRA-WAVE (store thread
// t reads granule 4t, owned by its own wave) -> NO __syncthreads; waves
// pipeline independently. Swizzle gives exactly 8 lanes/4-bank-group on both
// LDS write and read = conflict-free-optimal for b128.
// ---------------------------------------------------------------------------
__global__ __launch_bounds__(256, 2) void bitgemm(
    const float*          __restrict__ x,        // [65536][32]
    const unsigned short* __restrict__ wq,       // [1024][32] bf16 ternary
    const float*          __restrict__ add,      // [1024][1024] bias+pe
    const float*          __restrict__ partial,  // [8]
    float* __restrict__ out)                     // [65536][1024]
{
    __shared__ float lds[16 * 1024];    // 64 KB; wave-private 16 KB quadrants

    const int t    = threadIdx.x;
    const int lane = t & 63;
    const int wid  = t >> 6;
    const int l15  = lane & 15;
    const int hi   = lane >> 4;              // 0..3

    const int b    = blockIdx.x & 63;        // b minor: co-resident blocks share s
    const int s0   = (blockIdx.x >> 6) << 4; // 0,16,..,1008
    const int tok0 = (b << 10) + s0;
    const int oq   = wid << 8;               // wave o-base

    // ---- weight 1/scale from partials (uniform scalar path) ----
    float tot = 0.f;
    #pragma unroll
    for (int p = 0; p < 8; ++p) tot += partial[p];
    const float rw = fmaxf(tot * (1.0f / 32768.0f), 1e-5f);

    // ---- x load + activation quant (lanes {l15,+16,+32,+48} = one token) ----
    const float* xr = x + (size_t)(tok0 + l15) * KDIM + hi * 8;
    float4 xa = *reinterpret_cast<const float4*>(xr);
    float4 xb = *reinterpret_cast<const float4*>(xr + 4);
    float am = fmaxf(fmaxf(fmaxf(fabsf(xa.x), fabsf(xa.y)),
                           fmaxf(fabsf(xa.z), fabsf(xa.w))),
                     fmaxf(fmaxf(fabsf(xb.x), fabsf(xb.y)),
                           fmaxf(fabsf(xb.z), fabsf(xb.w))));
    am = fmaxf(am, __shfl_xor(am, 16));
    am = fmaxf(am, __shfl_xor(am, 32));
    am = fmaxf(am, 1e-5f);
    const float xscale = 127.0f / am;        // |v*scale| <= 127: clip can't bind
    union { bf16x8 v; unsigned short s[8]; } bu;
    {
        float e[8] = {xa.x, xa.y, xa.z, xa.w, xb.x, xb.y, xb.z, xb.w};
        #pragma unroll
        for (int j = 0; j < 8; ++j)
            bu.s[j] = f32_to_bf16_exact(rintf(e[j] * xscale)); // int in [-127,127]
    }
    const float rxw = am * (1.0f / 127.0f) * rw;   // combined 1/scales, per token

    // ---- 16 frags: wq load -> MFMA -> (add-table + scale) -> swizzled LDS ----
    #pragma unroll
    for (int f = 0; f < 16; ++f) {
        const int of = oq + f * 16;
        bf16x8 afrag = *reinterpret_cast<const bf16x8*>(
            wq + (size_t)(of + l15) * KDIM + hi * 8);

        f32x4 acc = (f32x4){0.f, 0.f, 0.f, 0.f};
        acc = __builtin_amdgcn_mfma_f32_16x16x32_bf16(afrag, bu.v, acc, 0, 0, 0);

        const int oe = of + hi * 4;
        f32x4 av = *reinterpret_cast<const f32x4*>(
            add + (size_t)(s0 + l15) * ODIM + oe);
        f32x4 r;
        #pragma unroll
        for (int j = 0; j < 4; ++j) r[j] = fmaf(acc[j], rxw, av[j]);
        // logical granule g -> physical g ^ (row&7); stays in wave's quadrant
        const int g = (oq >> 2) + f * 4 + hi;
        *reinterpret_cast<f32x4*>(&lds[(l15 << 10) + ((g ^ (l15 & 7)) << 2)]) = r;
    }

    // no __syncthreads: transpose is intra-wave (granule 4t is in wave wid's
    // o-range for t in [wid*64, wid*64+64)); lgkmcnt orders ds_write->ds_read.

    // ---- store: 16 rows; wave writes 1 KB contiguous per row, block = 4 KB ----
    float* ob = out + (size_t)tok0 * ODIM;
    #pragma unroll
    for (int c = 0; c < 16; ++c) {
        f32x4 v = *reinterpret_cast<const f32x4*>(
            &lds[(c << 10) + ((t ^ (c & 7)) << 2)]);
        *reinterpret_cast<f32x4*>(ob + (c << 10) + (t << 2)) = v;
    }
}

// ---------------------------------------------------------------------------
extern "C" void kernel_launch(void* const* d_in, const int* in_sizes, int n_in,
                              void* d_out, int out_size, void* d_ws, size_t ws_size,
                              hipStream_t stream) {
    const float* x = (const float*)d_in[0];   // [64][1024][32]
    const float* W = (const float*)d_in[1];   // [1024][32]
    const float* b = (const float*)d_in[2];   // [1024]
    float* out = (float*)d_out;

    // ws: partial f32[8] @0 | wq bf16[1024][32] @64B (64 KB) | add f32[1024][1024] @1MB
    char* wsb = (char*)d_ws;
    float*          partial = (float*)wsb;
    unsigned short* wq      = (unsigned short*)(wsb + 64);
    float*          add     = (float*)(wsb + (1u << 20));

    wpartial_kernel<<<8, 256, 0, stream>>>(W, partial);
    wquant_kernel<<<4, 256, 0, stream>>>(W, partial, wq);
    pe_bias_kernel<<<(SEQLEN * ODIM / 4) / 256, 256, 0, stream>>>(b, add);
    bitgemm<<<NTOK / 16, 256, 0, stream>>>(x, wq, add, partial, out);
}

// Round 7
// 75.152 us; speedup vs baseline: 2.3550x; 1.2241x over previous
//
#include <hip/hip_runtime.h>
#include <cstdint>
#include <cstddef>

// x[64][1024][32] f32, W[1024][32] f32, b[1024] f32 -> out[64][1024][1024] f32
#define BATCH   64
#define SEQLEN  1024
#define KDIM    32
#define ODIM    1024
#define NTOK    (BATCH * SEQLEN)

typedef __attribute__((ext_vector_type(8))) short bf16x8;   // 8 bf16 = 4 VGPRs
typedef __attribute__((ext_vector_type(4))) float f32x4;

// exact f32 -> bf16 truncation; exact for integer-valued f32 |v| <= 255 and {-1,0,1}
__device__ __forceinline__ unsigned short f32_to_bf16_exact(float f) {
    union { float f; unsigned int u; } cv; cv.f = f;
    return (unsigned short)(cv.u >> 16);
}

// ---------------------------------------------------------------------------
// Kernel 1: W |.| partial sums. 8 blocks x 256 threads x 16 contiguous elems.
// ---------------------------------------------------------------------------
__global__ __launch_bounds__(256) void wpartial_kernel(const float* __restrict__ W,
                                                       float* __restrict__ partial) {
    __shared__ float red[256];
    const int t = threadIdx.x;
    const float4* W4 = reinterpret_cast<const float4*>(W) + (size_t)blockIdx.x * 1024 + t * 4;
    float acc = 0.f;
    #pragma unroll
    for (int j = 0; j < 4; ++j) {
        float4 v = W4[j];
        acc += fabsf(v.x) + fabsf(v.y) + fabsf(v.z) + fabsf(v.w);
    }
    red[t] = acc;
    __syncthreads();
    for (int step = 128; step > 0; step >>= 1) {
        if (t < step) red[t] += red[t + step];
        __syncthreads();
    }
    if (t == 0) partial[blockIdx.x] = red[0];
}

// ---------------------------------------------------------------------------
// Kernel 2: activation quant -> xq bf16[tok][k] (INTEGER n in [-127,127]) and
// rxs[tok] = clip(absmax,1e-5)/127 * rw  (combined output scale, rw folded).
// ---------------------------------------------------------------------------
__global__ __launch_bounds__(256) void quant_x_kernel(const float* __restrict__ x,
                                                      const float* __restrict__ partial,
                                                      unsigned short* __restrict__ xq,
                                                      float* __restrict__ rxs) {
    const int idx = blockIdx.x * 256 + threadIdx.x;
    float v = x[idx];
    float a = fabsf(v);
    #pragma unroll
    for (int off = 1; off < 32; off <<= 1)
        a = fmaxf(a, __shfl_xor(a, off, 32));
    float am = fmaxf(a, 1e-5f);
    float scale = 127.0f / am;                  // |v*scale| <= 127: clip can't bind
    xq[idx] = f32_to_bf16_exact(rintf(v * scale));   // int, exact in bf16
    if ((idx & 31) == 0) {
        float tot = 0.f;
        #pragma unroll
        for (int p = 0; p < 8; ++p) tot += partial[p];
        float rw = fmaxf(tot * (1.0f / 32768.0f), 1e-5f);   // 1/scale_w
        rxs[idx >> 5] = am * (1.0f / 127.0f) * rw;
    }
}

// ---------------------------------------------------------------------------
// Kernel 3: add-table add[s][o] = bias[o] + pe(s,o), f32, 4 MB.
// f32 PE verified adequate (absmax 0.015625, threshold 7.2e-2, rounds 3-6).
// ---------------------------------------------------------------------------
__global__ __launch_bounds__(256) void pe_bias_kernel(const float* __restrict__ bias,
                                                      float* __restrict__ add) {
    const int g  = blockIdx.x * 256 + threadIdx.x;     // 16B granule index
    const int oe = (g << 2) & (ODIM - 1);              // multiple of 4
    const int s  = g >> 8;
    const float C = -0.012976281620653759f;            // -log2(10000)/1024
    const float sf = (float)s;
    float a0 = sf * exp2f(C * (float)oe);
    float a1 = sf * exp2f(C * (float)(oe + 2));
    f32x4 bv = *reinterpret_cast<const f32x4*>(bias + oe);
    f32x4 r;
    r[0] = bv[0] + sinf(a0);
    r[1] = bv[1] + cosf(a0);
    r[2] = bv[2] + sinf(a1);
    r[3] = bv[3] + cosf(a1);
    *reinterpret_cast<f32x4*>(add + ((size_t)g << 2)) = r;
}

// ---------------------------------------------------------------------------
// Kernel 4: BitLinear GEMM, b-amortized (round-2 structure, tuned).
// Tile: 16 s x 32 o x ALL 64 b per block; 4 waves, wave wid owns b in
// [wid*16, +16). Grid = 64 sblk x 32 oblk = 2048 blocks (8/CU available;
// VGPR ~70 -> ~6 resident -> ~24 waves/CU, 2x round 2). W ternary-quantized
// inline (once per wave, amortized over 16 b-iters). b-loop unrolled 4x so
// xq loads pipeline. Stores: per instr 16 token-rows x 64 B, 256 B/row
// completed across the 2 f's -> full L2 lines, coalesced writeback.
// ---------------------------------------------------------------------------
__global__ __launch_bounds__(256) void bitgemm(
    const unsigned short* __restrict__ xq,       // [65536][32] bf16 int
    const float*          __restrict__ rxs,      // [65536] combined scale
    const float*          __restrict__ W,        // [1024][32] f32
    const float*          __restrict__ partial,  // [8]
    const float*          __restrict__ add,      // [1024][1024] bias+pe
    float* __restrict__ out)                     // [65536][1024]
{
    const int lane = threadIdx.x & 63;
    const int wid  = threadIdx.x >> 6;
    const int l15  = lane & 15;
    const int hi   = lane >> 4;               // 0..3

    const int oblk = blockIdx.x & 31;         // fast index: same-s blocks adjacent
    const int sblk = blockIdx.x >> 5;
    const int o0   = oblk * 32;
    const int s0   = sblk * 16;

    // ---- weight scale (uniform scalar path) ----
    float tot = 0.f;
    #pragma unroll
    for (int p = 0; p < 8; ++p) tot += partial[p];
    const float sc = 1.0f / fmaxf(tot * (1.0f / 32768.0f), 1e-5f);

    // ---- A fragments: inline ternary quant of W (once per wave) ----
    bf16x8 afrag[2];
    #pragma unroll
    for (int f = 0; f < 2; ++f) {
        const float* wr = W + (size_t)(o0 + f * 16 + l15) * KDIM + hi * 8;
        float4 wa = *reinterpret_cast<const float4*>(wr);
        float4 wb = *reinterpret_cast<const float4*>(wr + 4);
        float e[8] = {wa.x, wa.y, wa.z, wa.w, wb.x, wb.y, wb.z, wb.w};
        union { bf16x8 v; unsigned short s[8]; } u;
        #pragma unroll
        for (int j = 0; j < 8; ++j)
            u.s[j] = f32_to_bf16_exact(fminf(fmaxf(rintf(e[j] * sc), -1.0f), 1.0f));
        afrag[f] = u.v;
    }

    // ---- bias+pe fragments (hoisted; add rows L2-hot across 32 o-blocks) ----
    f32x4 addf[2];
    #pragma unroll
    for (int f = 0; f < 2; ++f)
        addf[f] = *reinterpret_cast<const f32x4*>(
            add + (size_t)(s0 + l15) * ODIM + o0 + f * 16 + hi * 4);

    // ---- b-loop: 16 iterations, 4x unrolled for load pipelining ----
    #pragma unroll 4
    for (int i = 0; i < 16; ++i) {
        const int b   = wid * 16 + i;
        const int tok = (b << 10) + s0 + l15;

        bf16x8 bfrag = *reinterpret_cast<const bf16x8*>(
            xq + ((size_t)tok << 5) + hi * 8);
        const float rxw = rxs[tok];

        float* op = out + ((size_t)tok << 10) + o0 + hi * 4;
        #pragma unroll
        for (int f = 0; f < 2; ++f) {
            f32x4 acc = (f32x4){0.f, 0.f, 0.f, 0.f};
            acc = __builtin_amdgcn_mfma_f32_16x16x32_bf16(afrag[f], bfrag, acc, 0, 0, 0);
            f32x4 r;
            #pragma unroll
            for (int j = 0; j < 4; ++j)
                r[j] = fmaf(acc[j], rxw, addf[f][j]);
            *reinterpret_cast<f32x4*>(op + f * 16) = r;
        }
    }
}

// ---------------------------------------------------------------------------
extern "C" void kernel_launch(void* const* d_in, const int* in_sizes, int n_in,
                              void* d_out, int out_size, void* d_ws, size_t ws_size,
                              hipStream_t stream) {
    const float* x = (const float*)d_in[0];   // [64][1024][32]
    const float* W = (const float*)d_in[1];   // [1024][32]
    const float* b = (const float*)d_in[2];   // [1024]
    float* out = (float*)d_out;

    // ws: partial f32[8] @0 | rxs f32[65536] @256B | xq bf16[65536][32] @512KB
    //     add f32[1024][1024] @8MB
    char* wsb = (char*)d_ws;
    float*          partial = (float*)wsb;
    float*          rxs     = (float*)(wsb + 256);
    unsigned short* xq      = (unsigned short*)(wsb + (512u << 10));
    float*          add     = (float*)(wsb + (8u << 20));

    wpartial_kernel<<<8, 256, 0, stream>>>(W, partial);
    quant_x_kernel<<<(NTOK * KDIM) / 256, 256, 0, stream>>>(x, partial, xq, rxs);
    pe_bias_kernel<<<(SEQLEN * ODIM / 4) / 256, 256, 0, stream>>>(b, add);
    bitgemm<<<64 * 32, 256, 0, stream>>>(xq, rxs, W, partial, add, out);
}

// Round 8
// 66.459 us; speedup vs baseline: 2.6630x; 1.1308x over previous
//
#include <hip/hip_runtime.h>
#include <cstdint>
#include <cstddef>

// x[64][1024][32] f32, W[1024][32] f32, b[1024] f32 -> out[64][1024][1024] f32
#define BATCH   64
#define SEQLEN  1024
#define KDIM    32
#define ODIM    1024
#define NTOK    (BATCH * SEQLEN)

#define NWP 8        // wpartial blocks
#define NQX 8192     // quant_x blocks (65536*32 / 256)
#define NPE 1024     // pe_bias blocks (1024*1024/4 / 256)

typedef __attribute__((ext_vector_type(8))) short bf16x8;   // 8 bf16 = 4 VGPRs
typedef __attribute__((ext_vector_type(4))) float f32x4;

// exact f32 -> bf16 truncation; exact for integer-valued f32 |v| <= 255 and {-1,0,1}
__device__ __forceinline__ unsigned short f32_to_bf16_exact(float f) {
    union { float f; unsigned int u; } cv; cv.f = f;
    return (unsigned short)(cv.u >> 16);
}

// ---------------------------------------------------------------------------
// Kernel 1: merged prep — three independent jobs dispatched by block range.
//   blocks [0,8):            W |.| partial sums (deterministic tree reduce)
//   blocks [8, 8+8192):      activation quant -> xq (int bf16), rxs = am/127
//   blocks [8+8192, +1024):  add-table add[s][o] = bias[o] + pe(s,o)
// quant_x no longer folds rw into rxs, so all three are independent; the
// gemm multiplies rxs[tok]*rw itself (rw derived from partial there).
// ---------------------------------------------------------------------------
__global__ __launch_bounds__(256) void prep_kernel(const float* __restrict__ x,
                                                   const float* __restrict__ W,
                                                   const float* __restrict__ bias,
                                                   float* __restrict__ partial,
                                                   unsigned short* __restrict__ xq,
                                                   float* __restrict__ rxs,
                                                   float* __restrict__ add) {
    const int blk = blockIdx.x;
    const int t   = threadIdx.x;

    if (blk < NWP) {
        // ---- W |.| partial sums: 8 blocks x 256 threads x 16 elems ----
        __shared__ float red[256];
        const float4* W4 = reinterpret_cast<const float4*>(W) + (size_t)blk * 1024 + t * 4;
        float acc = 0.f;
        #pragma unroll
        for (int j = 0; j < 4; ++j) {
            float4 v = W4[j];
            acc += fabsf(v.x) + fabsf(v.y) + fabsf(v.z) + fabsf(v.w);
        }
        red[t] = acc;
        __syncthreads();
        for (int step = 128; step > 0; step >>= 1) {
            if (t < step) red[t] += red[t + step];
            __syncthreads();
        }
        if (t == 0) partial[blk] = red[0];
    } else if (blk < NWP + NQX) {
        // ---- activation quant (token = 32 contiguous elems; 32-lane groups) ----
        const int idx = (blk - NWP) * 256 + t;
        float v = x[idx];
        float a = fabsf(v);
        #pragma unroll
        for (int off = 1; off < 32; off <<= 1)
            a = fmaxf(a, __shfl_xor(a, off, 32));
        float am = fmaxf(a, 1e-5f);
        float scale = 127.0f / am;                 // |v*scale| <= 127: clip can't bind
        xq[idx] = f32_to_bf16_exact(rintf(v * scale));   // int, exact in bf16
        if ((idx & 31) == 0) rxs[idx >> 5] = am * (1.0f / 127.0f);
    } else {
        // ---- add-table: bias + f32 positional encoding (verified adequate) ----
        const int g  = (blk - NWP - NQX) * 256 + t;    // 16B granule index
        const int oe = (g << 2) & (ODIM - 1);          // multiple of 4
        const int s  = g >> 8;
        const float C = -0.012976281620653759f;        // -log2(10000)/1024
        const float sf = (float)s;
        float a0 = sf * exp2f(C * (float)oe);
        float a1 = sf * exp2f(C * (float)(oe + 2));
        f32x4 bv = *reinterpret_cast<const f32x4*>(bias + oe);
        f32x4 r;
        r[0] = bv[0] + sinf(a0);
        r[1] = bv[1] + cosf(a0);
        r[2] = bv[2] + sinf(a1);
        r[3] = bv[3] + cosf(a1);
        *reinterpret_cast<f32x4*>(add + ((size_t)g << 2)) = r;
    }
}

// ---------------------------------------------------------------------------
// Kernel 2: BitLinear GEMM, b-amortized + XCD-aware swizzle.
// Logical tile: 16 s x 32 o x ALL 64 b per block; 4 waves, wave wid owns b in
// [wid*16,+16). Grid = 2048. XCD swizzle lb=(phys&7)*256+(phys>>3): blocks on
// XCD k cover s-chunks [8k,8k+8) x all o-blocks, so each XCD's xq slice
// (512 KB) and add slice (512 KB) are HBM-fetched once CHIP-WIDE (was: once
// per XCD, 8x duplication). W ternary-quantized inline once per wave.
// ---------------------------------------------------------------------------
__global__ __launch_bounds__(256) void bitgemm(
    const unsigned short* __restrict__ xq,       // [65536][32] bf16 int
    const float*          __restrict__ rxs,      // [65536] am/127
    const float*          __restrict__ W,        // [1024][32] f32
    const float*          __restrict__ partial,  // [8]
    const float*          __restrict__ add,      // [1024][1024] bias+pe
    float* __restrict__ out)                     // [65536][1024]
{
    const int lane = threadIdx.x & 63;
    const int wid  = threadIdx.x >> 6;
    const int l15  = lane & 15;
    const int hi   = lane >> 4;               // 0..3

    // XCD-aware swizzle (bijective: 2048 = 8 XCDs x 256)
    const int lb   = (blockIdx.x & 7) * 256 + (blockIdx.x >> 3);
    const int oblk = lb & 31;                 // o-blocks adjacent within an XCD
    const int sblk = lb >> 5;
    const int o0   = oblk * 32;
    const int s0   = sblk * 16;

    // ---- weight scale from partials (uniform scalar path) ----
    float tot = 0.f;
    #pragma unroll
    for (int p = 0; p < 8; ++p) tot += partial[p];
    const float rw = fmaxf(tot * (1.0f / 32768.0f), 1e-5f);   // 1/scale_w
    const float sc = 1.0f / rw;                               // scale_w

    // ---- A fragments: inline ternary quant of W (once per wave) ----
    bf16x8 afrag[2];
    #pragma unroll
    for (int f = 0; f < 2; ++f) {
        const float* wr = W + (size_t)(o0 + f * 16 + l15) * KDIM + hi * 8;
        float4 wa = *reinterpret_cast<const float4*>(wr);
        float4 wb = *reinterpret_cast<const float4*>(wr + 4);
        float e[8] = {wa.x, wa.y, wa.z, wa.w, wb.x, wb.y, wb.z, wb.w};
        union { bf16x8 v; unsigned short s[8]; } u;
        #pragma unroll
        for (int j = 0; j < 8; ++j)
            u.s[j] = f32_to_bf16_exact(fminf(fmaxf(rintf(e[j] * sc), -1.0f), 1.0f));
        afrag[f] = u.v;
    }

    // ---- bias+pe fragments (hoisted; add rows L2-hot within the XCD) ----
    f32x4 addf[2];
    #pragma unroll
    for (int f = 0; f < 2; ++f)
        addf[f] = *reinterpret_cast<const f32x4*>(
            add + (size_t)(s0 + l15) * ODIM + o0 + f * 16 + hi * 4);

    // ---- b-loop: 16 iterations, 4x unrolled for load pipelining ----
    #pragma unroll 4
    for (int i = 0; i < 16; ++i) {
        const int b   = wid * 16 + i;
        const int tok = (b << 10) + s0 + l15;

        bf16x8 bfrag = *reinterpret_cast<const bf16x8*>(
            xq + ((size_t)tok << 5) + hi * 8);
        const float rxw = rxs[tok] * rw;

        float* op = out + ((size_t)tok << 10) + o0 + hi * 4;
        #pragma unroll
        for (int f = 0; f < 2; ++f) {
            f32x4 acc = (f32x4){0.f, 0.f, 0.f, 0.f};
            acc = __builtin_amdgcn_mfma_f32_16x16x32_bf16(afrag[f], bfrag, acc, 0, 0, 0);
            f32x4 r;
            #pragma unroll
            for (int j = 0; j < 4; ++j)
                r[j] = fmaf(acc[j], rxw, addf[f][j]);
            *reinterpret_cast<f32x4*>(op + f * 16) = r;
        }
    }
}

// ---------------------------------------------------------------------------
extern "C" void kernel_launch(void* const* d_in, const int* in_sizes, int n_in,
                              void* d_out, int out_size, void* d_ws, size_t ws_size,
                              hipStream_t stream) {
    const float* x = (const float*)d_in[0];   // [64][1024][32]
    const float* W = (const float*)d_in[1];   // [1024][32]
    const float* b = (const float*)d_in[2];   // [1024]
    float* out = (float*)d_out;

    // ws: partial f32[8] @0 | rxs f32[65536] @256B | xq bf16[65536][32] @512KB
    //     add f32[1024][1024] @8MB
    char* wsb = (char*)d_ws;
    float*          partial = (float*)wsb;
    float*          rxs     = (float*)(wsb + 256);
    unsigned short* xq      = (unsigned short*)(wsb + (512u << 10));
    float*          add     = (float*)(wsb + (8u << 20));

    prep_kernel<<<NWP + NQX + NPE, 256, 0, stream>>>(x, W, b, partial, xq, rxs, add);
    bitgemm<<<2048, 256, 0, stream>>>(xq, rxs, W, partial, add, out);
}

// Round 9
// 62.177 us; speedup vs baseline: 2.8464x; 1.0689x over previous
//
#include <hip/hip_runtime.h>
#include <cstdint>
#include <cstddef>

// x[64][1024][32] f32, W[1024][32] f32, b[1024] f32 -> out[64][1024][1024] f32
#define BATCH   64
#define SEQLEN  1024
#define KDIM    32
#define ODIM    1024
#define NTOK    (BATCH * SEQLEN)

#define NWP 8        // wpartial blocks
#define NQX 1024     // quant_x blocks (65536*32 / 8 elems-per-thread / 256)

typedef __attribute__((ext_vector_type(8))) short bf16x8;   // 8 bf16 = 4 VGPRs
typedef __attribute__((ext_vector_type(4))) float f32x4;

// exact f32 -> bf16 truncation; exact for integer-valued f32 |v| <= 255 and {-1,0,1}
__device__ __forceinline__ unsigned short f32_to_bf16_exact(float f) {
    union { float f; unsigned int u; } cv; cv.f = f;
    return (unsigned short)(cv.u >> 16);
}

// ---------------------------------------------------------------------------
// Kernel 1: merged prep — two independent jobs dispatched by block range.
//   blocks [0,8):        W |.| partial sums (deterministic tree reduce)
//   blocks [8, 8+1024):  activation quant x8-vectorized -> xq int bf16,
//                        rxs = clip(absmax,1e-5)/127
// ---------------------------------------------------------------------------
__global__ __launch_bounds__(256) void prep_kernel(const float* __restrict__ x,
                                                   const float* __restrict__ W,
                                                   float* __restrict__ partial,
                                                   unsigned short* __restrict__ xq,
                                                   float* __restrict__ rxs) {
    const int blk = blockIdx.x;
    const int t   = threadIdx.x;

    if (blk < NWP) {
        // ---- W |.| partial sums: 8 blocks x 256 threads x 16 elems ----
        __shared__ float red[256];
        const float4* W4 = reinterpret_cast<const float4*>(W) + (size_t)blk * 1024 + t * 4;
        float acc = 0.f;
        #pragma unroll
        for (int j = 0; j < 4; ++j) {
            float4 v = W4[j];
            acc += fabsf(v.x) + fabsf(v.y) + fabsf(v.z) + fabsf(v.w);
        }
        red[t] = acc;
        __syncthreads();
        for (int step = 128; step > 0; step >>= 1) {
            if (t < step) red[t] += red[t + step];
            __syncthreads();
        }
        if (t == 0) partial[blk] = red[0];
    } else {
        // ---- activation quant: thread owns 8 elems; 4 threads = 1 token ----
        const int g = (blk - NWP) * 256 + t;         // 8-elem group index
        const float* xg = x + ((size_t)g << 3);
        float4 xa = *reinterpret_cast<const float4*>(xg);
        float4 xb = *reinterpret_cast<const float4*>(xg + 4);
        float a = fmaxf(fmaxf(fmaxf(fabsf(xa.x), fabsf(xa.y)),
                              fmaxf(fabsf(xa.z), fabsf(xa.w))),
                        fmaxf(fmaxf(fabsf(xb.x), fabsf(xb.y)),
                              fmaxf(fabsf(xb.z), fabsf(xb.w))));
        a = fmaxf(a, __shfl_xor(a, 1, 4));           // 4-lane token group
        a = fmaxf(a, __shfl_xor(a, 2, 4));
        const float am = fmaxf(a, 1e-5f);
        const float scale = 127.0f / am;             // |v*scale|<=127: clip can't bind
        float e[8] = {xa.x, xa.y, xa.z, xa.w, xb.x, xb.y, xb.z, xb.w};
        union { bf16x8 v; unsigned short s[8]; } u;
        #pragma unroll
        for (int j = 0; j < 8; ++j)
            u.s[j] = f32_to_bf16_exact(rintf(e[j] * scale));   // int, exact bf16
        *reinterpret_cast<bf16x8*>(xq + ((size_t)g << 3)) = u.v;
        if ((g & 3) == 0) rxs[g >> 2] = am * (1.0f / 127.0f);
    }
}

// ---------------------------------------------------------------------------
// Kernel 2: BitLinear GEMM, b-amortized + XCD swizzle + inline PE epilogue.
// Tile: 16 s x 32 o x ALL 64 b; 4 waves, wave wid owns b in [wid*16,+16).
// Grid 2048, swizzle lb=(phys&7)*256+(phys>>3): XCD k owns s-chunks
// [8k,8k+8) x all o -> its xq slice fetched once chip-wide. W ternary-
// quantized inline once per wave; bias+PE computed in-register once per
// block (f32: absmax 0.015625 across rounds 3-8, threshold 7.2e-2).
// ---------------------------------------------------------------------------
__global__ __launch_bounds__(256) void bitgemm(
    const unsigned short* __restrict__ xq,       // [65536][32] bf16 int
    const float*          __restrict__ rxs,      // [65536] am/127
    const float*          __restrict__ W,        // [1024][32] f32
    const float*          __restrict__ partial,  // [8]
    const float*          __restrict__ bias,     // [1024]
    float* __restrict__ out)                     // [65536][1024]
{
    const int lane = threadIdx.x & 63;
    const int wid  = threadIdx.x >> 6;
    const int l15  = lane & 15;
    const int hi   = lane >> 4;               // 0..3

    // XCD-aware swizzle (bijective: 2048 = 8 XCDs x 256)
    const int lb   = (blockIdx.x & 7) * 256 + (blockIdx.x >> 3);
    const int oblk = lb & 31;                 // o-blocks adjacent within an XCD
    const int sblk = lb >> 5;
    const int o0   = oblk * 32;
    const int s0   = sblk * 16;

    // ---- weight scale from partials (uniform scalar path) ----
    float tot = 0.f;
    #pragma unroll
    for (int p = 0; p < 8; ++p) tot += partial[p];
    const float rw = fmaxf(tot * (1.0f / 32768.0f), 1e-5f);   // 1/scale_w
    const float sc = 1.0f / rw;                               // scale_w

    // ---- A fragments: inline ternary quant of W (once per wave) ----
    bf16x8 afrag[2];
    #pragma unroll
    for (int f = 0; f < 2; ++f) {
        const float* wr = W + (size_t)(o0 + f * 16 + l15) * KDIM + hi * 8;
        float4 wa = *reinterpret_cast<const float4*>(wr);
        float4 wb = *reinterpret_cast<const float4*>(wr + 4);
        float e[8] = {wa.x, wa.y, wa.z, wa.w, wb.x, wb.y, wb.z, wb.w};
        union { bf16x8 v; unsigned short s[8]; } u;
        #pragma unroll
        for (int j = 0; j < 8; ++j)
            u.s[j] = f32_to_bf16_exact(fminf(fmaxf(rintf(e[j] * sc), -1.0f), 1.0f));
        afrag[f] = u.v;
    }

    // ---- bias + positional encoding in-register (once per block) ----
    const float C  = -0.012976281620653759f;  // -log2(10000)/1024
    const float sf = (float)(s0 + l15);
    f32x4 addf[2];
    #pragma unroll
    for (int f = 0; f < 2; ++f) {
        const int oe = o0 + f * 16 + hi * 4;              // multiple of 4
        f32x4 bv = *reinterpret_cast<const f32x4*>(bias + oe);
        float a0 = sf * exp2f(C * (float)oe);
        float a1 = sf * exp2f(C * (float)(oe + 2));
        addf[f][0] = bv[0] + sinf(a0);
        addf[f][1] = bv[1] + cosf(a0);
        addf[f][2] = bv[2] + sinf(a1);
        addf[f][3] = bv[3] + cosf(a1);
    }

    // ---- b-loop: 16 iterations, 4x unrolled for load pipelining ----
    #pragma unroll 4
    for (int i = 0; i < 16; ++i) {
        const int b   = wid * 16 + i;
        const int tok = (b << 10) + s0 + l15;

        bf16x8 bfrag = *reinterpret_cast<const bf16x8*>(
            xq + ((size_t)tok << 5) + hi * 8);
        const float rxw = rxs[tok] * rw;

        float* op = out + ((size_t)tok << 10) + o0 + hi * 4;
        #pragma unroll
        for (int f = 0; f < 2; ++f) {
            f32x4 acc = (f32x4){0.f, 0.f, 0.f, 0.f};
            acc = __builtin_amdgcn_mfma_f32_16x16x32_bf16(afrag[f], bfrag, acc, 0, 0, 0);
            f32x4 r;
            #pragma unroll
            for (int j = 0; j < 4; ++j)
                r[j] = fmaf(acc[j], rxw, addf[f][j]);
            *reinterpret_cast<f32x4*>(op + f * 16) = r;
        }
    }
}

// ---------------------------------------------------------------------------
extern "C" void kernel_launch(void* const* d_in, const int* in_sizes, int n_in,
                              void* d_out, int out_size, void* d_ws, size_t ws_size,
                              hipStream_t stream) {
    const float* x = (const float*)d_in[0];   // [64][1024][32]
    const float* W = (const float*)d_in[1];   // [1024][32]
    const float* b = (const float*)d_in[2];   // [1024]
    float* out = (float*)d_out;

    // ws: partial f32[8] @0 | rxs f32[65536] @256B | xq bf16[65536][32] @512KB
    char* wsb = (char*)d_ws;
    float*          partial = (float*)wsb;
    float*          rxs     = (float*)(wsb + 256);
    unsigned short* xq      = (unsigned short*)(wsb + (512u << 10));

    prep_kernel<<<NWP + NQX, 256, 0, stream>>>(x, W, partial, xq, rxs);
    bitgemm<<<2048, 256, 0, stream>>>(xq, rxs, W, partial, b, out);
}

// Round 10
// 60.227 us; speedup vs baseline: 2.9385x; 1.0324x over previous
//
#include <hip/hip_runtime.h>
#include <cstdint>
#include <cstddef>

// x[64][1024][32] f32, W[1024][32] f32, b[1024] f32 -> out[64][1024][1024] f32
#define BATCH   64
#define SEQLEN  1024
#define KDIM    32
#define ODIM    1024
#define NTOK    (BATCH * SEQLEN)

#define NWP 8        // wpartial blocks
#define NQX 1024     // quant_x blocks (65536*32 / 8 elems-per-thread / 256)

typedef __attribute__((ext_vector_type(8))) short bf16x8;   // 8 bf16 = 4 VGPRs
typedef __attribute__((ext_vector_type(4))) float f32x4;

// exact f32 -> bf16 truncation; exact for integer-valued f32 |v| <= 255 and {-1,0,1}
__device__ __forceinline__ unsigned short f32_to_bf16_exact(float f) {
    union { float f; unsigned int u; } cv; cv.f = f;
    return (unsigned short)(cv.u >> 16);
}

// ---------------------------------------------------------------------------
// Kernel 1: merged prep — two independent jobs dispatched by block range.
//   blocks [0,8):        W |.| partial sums (deterministic tree reduce)
//   blocks [8, 8+1024):  activation quant x8-vectorized -> xq int bf16,
//                        rxs = clip(absmax,1e-5)/127
// ---------------------------------------------------------------------------
__global__ __launch_bounds__(256) void prep_kernel(const float* __restrict__ x,
                                                   const float* __restrict__ W,
                                                   float* __restrict__ partial,
                                                   unsigned short* __restrict__ xq,
                                                   float* __restrict__ rxs) {
    const int blk = blockIdx.x;
    const int t   = threadIdx.x;

    if (blk < NWP) {
        // ---- W |.| partial sums: 8 blocks x 256 threads x 16 elems ----
        __shared__ float red[256];
        const float4* W4 = reinterpret_cast<const float4*>(W) + (size_t)blk * 1024 + t * 4;
        float acc = 0.f;
        #pragma unroll
        for (int j = 0; j < 4; ++j) {
            float4 v = W4[j];
            acc += fabsf(v.x) + fabsf(v.y) + fabsf(v.z) + fabsf(v.w);
        }
        red[t] = acc;
        __syncthreads();
        for (int step = 128; step > 0; step >>= 1) {
            if (t < step) red[t] += red[t + step];
            __syncthreads();
        }
        if (t == 0) partial[blk] = red[0];
    } else {
        // ---- activation quant: thread owns 8 elems; 4 threads = 1 token ----
        const int g = (blk - NWP) * 256 + t;         // 8-elem group index
        const float* xg = x + ((size_t)g << 3);
        float4 xa = *reinterpret_cast<const float4*>(xg);
        float4 xb = *reinterpret_cast<const float4*>(xg + 4);
        float a = fmaxf(fmaxf(fmaxf(fabsf(xa.x), fabsf(xa.y)),
                              fmaxf(fabsf(xa.z), fabsf(xa.w))),
                        fmaxf(fmaxf(fabsf(xb.x), fabsf(xb.y)),
                              fmaxf(fabsf(xb.z), fabsf(xb.w))));
        a = fmaxf(a, __shfl_xor(a, 1, 4));           // 4-lane token group
        a = fmaxf(a, __shfl_xor(a, 2, 4));
        const float am = fmaxf(a, 1e-5f);
        const float scale = 127.0f / am;             // |v*scale|<=127: clip can't bind
        float e[8] = {xa.x, xa.y, xa.z, xa.w, xb.x, xb.y, xb.z, xb.w};
        union { bf16x8 v; unsigned short s[8]; } u;
        #pragma unroll
        for (int j = 0; j < 8; ++j)
            u.s[j] = f32_to_bf16_exact(rintf(e[j] * scale));   // int, exact bf16
        *reinterpret_cast<bf16x8*>(xq + ((size_t)g << 3)) = u.v;
        if ((g & 3) == 0) rxs[g >> 2] = am * (1.0f / 127.0f);
    }
}

// ---------------------------------------------------------------------------
// Kernel 2: BitLinear GEMM — round-9 structure, o-tile widened 32 -> 64.
// Tile: 16 s x 64 o x ALL 64 b; 4 waves, wave wid owns b in [wid*16,+16).
// Grid 1024 (= 8 XCD x 128), swizzle lb=(phys&7)*128+(phys>>3): XCD k owns
// s-chunks [8k,8k+8) x all 16 o-blocks -> disjoint xq slice, fetched once.
// Per iteration a wave completes 256 B per output row (vs 128 B in r9) and
// only 16 blocks share a row's L2 assembly (vs 32) -> better write locality.
// Occupancy 4 blocks/CU (16 waves/CU) — enough for a store-bound kernel.
// ---------------------------------------------------------------------------
__global__ __launch_bounds__(256) void bitgemm(
    const unsigned short* __restrict__ xq,       // [65536][32] bf16 int
    const float*          __restrict__ rxs,      // [65536] am/127
    const float*          __restrict__ W,        // [1024][32] f32
    const float*          __restrict__ partial,  // [8]
    const float*          __restrict__ bias,     // [1024]
    float* __restrict__ out)                     // [65536][1024]
{
    const int lane = threadIdx.x & 63;
    const int wid  = threadIdx.x >> 6;
    const int l15  = lane & 15;
    const int hi   = lane >> 4;               // 0..3

    // XCD-aware swizzle (bijective: 1024 = 8 XCDs x 128)
    const int lb   = (blockIdx.x & 7) * 128 + (blockIdx.x >> 3);
    const int oblk = lb & 15;                 // o-blocks adjacent within an XCD
    const int sblk = lb >> 4;
    const int o0   = oblk * 64;
    const int s0   = sblk * 16;

    // ---- weight scale from partials (uniform scalar path) ----
    float tot = 0.f;
    #pragma unroll
    for (int p = 0; p < 8; ++p) tot += partial[p];
    const float rw = fmaxf(tot * (1.0f / 32768.0f), 1e-5f);   // 1/scale_w
    const float sc = 1.0f / rw;                               // scale_w

    // ---- A fragments: inline ternary quant of W (once per wave) ----
    bf16x8 afrag[4];
    #pragma unroll
    for (int f = 0; f < 4; ++f) {
        const float* wr = W + (size_t)(o0 + f * 16 + l15) * KDIM + hi * 8;
        float4 wa = *reinterpret_cast<const float4*>(wr);
        float4 wb = *reinterpret_cast<const float4*>(wr + 4);
        float e[8] = {wa.x, wa.y, wa.z, wa.w, wb.x, wb.y, wb.z, wb.w};
        union { bf16x8 v; unsigned short s[8]; } u;
        #pragma unroll
        for (int j = 0; j < 8; ++j)
            u.s[j] = f32_to_bf16_exact(fminf(fmaxf(rintf(e[j] * sc), -1.0f), 1.0f));
        afrag[f] = u.v;
    }

    // ---- bias + positional encoding in-register (once per block) ----
    const float C  = -0.012976281620653759f;  // -log2(10000)/1024
    const float sf = (float)(s0 + l15);
    f32x4 addf[4];
    #pragma unroll
    for (int f = 0; f < 4; ++f) {
        const int oe = o0 + f * 16 + hi * 4;              // multiple of 4
        f32x4 bv = *reinterpret_cast<const f32x4*>(bias + oe);
        float a0 = sf * exp2f(C * (float)oe);
        float a1 = sf * exp2f(C * (float)(oe + 2));
        addf[f][0] = bv[0] + sinf(a0);
        addf[f][1] = bv[1] + cosf(a0);
        addf[f][2] = bv[2] + sinf(a1);
        addf[f][3] = bv[3] + cosf(a1);
    }

    // ---- b-loop: 16 iterations, 2x unrolled (8 stores / 2 loads in flight) ----
    #pragma unroll 2
    for (int i = 0; i < 16; ++i) {
        const int b   = wid * 16 + i;
        const int tok = (b << 10) + s0 + l15;

        bf16x8 bfrag = *reinterpret_cast<const bf16x8*>(
            xq + ((size_t)tok << 5) + hi * 8);
        const float rxw = rxs[tok] * rw;

        float* op = out + ((size_t)tok << 10) + o0 + hi * 4;
        #pragma unroll
        for (int f = 0; f < 4; ++f) {
            f32x4 acc = (f32x4){0.f, 0.f, 0.f, 0.f};
            acc = __builtin_amdgcn_mfma_f32_16x16x32_bf16(afrag[f], bfrag, acc, 0, 0, 0);
            f32x4 r;
            #pragma unroll
            for (int j = 0; j < 4; ++j)
                r[j] = fmaf(acc[j], rxw, addf[f][j]);
            *reinterpret_cast<f32x4*>(op + f * 16) = r;
        }
    }
}

// ---------------------------------------------------------------------------
extern "C" void kernel_launch(void* const* d_in, const int* in_sizes, int n_in,
                              void* d_out, int out_size, void* d_ws, size_t ws_size,
                              hipStream_t stream) {
    const float* x = (const float*)d_in[0];   // [64][1024][32]
    const float* W = (const float*)d_in[1];   // [1024][32]
    const float* b = (const float*)d_in[2];   // [1024]
    float* out = (float*)d_out;

    // ws: partial f32[8] @0 | rxs f32[65536] @256B | xq bf16[65536][32] @512KB
    char* wsb = (char*)d_ws;
    float*          partial = (float*)wsb;
    float*          rxs     = (float*)(wsb + 256);
    unsigned short* xq      = (unsigned short*)(wsb + (512u << 10));

    prep_kernel<<<NWP + NQX, 256, 0, stream>>>(x, W, partial, xq, rxs);
    bitgemm<<<1024, 256, 0, stream>>>(xq, rxs, W, partial, b, out);
}

// Round 11
// 56.550 us; speedup vs baseline: 3.1296x; 1.0650x over previous
//
#include <hip/hip_runtime.h>
#include <cstdint>
#include <cstddef>

// x[64][1024][32] f32, W[1024][32] f32, b[1024] f32 -> out[64][1024][1024] f32
#define BATCH   64
#define SEQLEN  1024
#define KDIM    32
#define ODIM    1024
#define NTOK    (BATCH * SEQLEN)

#define NWP 8        // wpartial blocks
#define NQX 1024     // quant_x blocks (65536*32 / 8 elems-per-thread / 256)

typedef __attribute__((ext_vector_type(8))) short bf16x8;   // 8 bf16 = 4 VGPRs
typedef __attribute__((ext_vector_type(4))) float f32x4;

// exact f32 -> bf16 truncation; exact for integer-valued f32 |v| <= 255 and {-1,0,1}
__device__ __forceinline__ unsigned short f32_to_bf16_exact(float f) {
    union { float f; unsigned int u; } cv; cv.f = f;
    return (unsigned short)(cv.u >> 16);
}

// ---------------------------------------------------------------------------
// Kernel 1: merged prep — two independent jobs dispatched by block range.
//   blocks [0,8):        W |.| partial sums (deterministic tree reduce)
//   blocks [8, 8+1024):  activation quant x8-vectorized -> xq int bf16,
//                        rxs = clip(absmax,1e-5)/127
// ---------------------------------------------------------------------------
__global__ __launch_bounds__(256) void prep_kernel(const float* __restrict__ x,
                                                   const float* __restrict__ W,
                                                   float* __restrict__ partial,
                                                   unsigned short* __restrict__ xq,
                                                   float* __restrict__ rxs) {
    const int blk = blockIdx.x;
    const int t   = threadIdx.x;

    if (blk < NWP) {
        // ---- W |.| partial sums: 8 blocks x 256 threads x 16 elems ----
        __shared__ float red[256];
        const float4* W4 = reinterpret_cast<const float4*>(W) + (size_t)blk * 1024 + t * 4;
        float acc = 0.f;
        #pragma unroll
        for (int j = 0; j < 4; ++j) {
            float4 v = W4[j];
            acc += fabsf(v.x) + fabsf(v.y) + fabsf(v.z) + fabsf(v.w);
        }
        red[t] = acc;
        __syncthreads();
        for (int step = 128; step > 0; step >>= 1) {
            if (t < step) red[t] += red[t + step];
            __syncthreads();
        }
        if (t == 0) partial[blk] = red[0];
    } else {
        // ---- activation quant: thread owns 8 elems; 4 threads = 1 token ----
        const int g = (blk - NWP) * 256 + t;         // 8-elem group index
        const float* xg = x + ((size_t)g << 3);
        float4 xa = *reinterpret_cast<const float4*>(xg);
        float4 xb = *reinterpret_cast<const float4*>(xg + 4);
        float a = fmaxf(fmaxf(fmaxf(fabsf(xa.x), fabsf(xa.y)),
                              fmaxf(fabsf(xa.z), fabsf(xa.w))),
                        fmaxf(fmaxf(fabsf(xb.x), fabsf(xb.y)),
                              fmaxf(fabsf(xb.z), fabsf(xb.w))));
        a = fmaxf(a, __shfl_xor(a, 1, 4));           // 4-lane token group
        a = fmaxf(a, __shfl_xor(a, 2, 4));
        const float am = fmaxf(a, 1e-5f);
        const float scale = 127.0f / am;             // |v*scale|<=127: clip can't bind
        float e[8] = {xa.x, xa.y, xa.z, xa.w, xb.x, xb.y, xb.z, xb.w};
        union { bf16x8 v; unsigned short s[8]; } u;
        #pragma unroll
        for (int j = 0; j < 8; ++j)
            u.s[j] = f32_to_bf16_exact(rintf(e[j] * scale));   // int, exact bf16
        *reinterpret_cast<bf16x8*>(xq + ((size_t)g << 3)) = u.v;
        if ((g & 3) == 0) rxs[g >> 2] = am * (1.0f / 127.0f);
    }
}

// ---------------------------------------------------------------------------
// Kernel 2: BitLinear GEMM — 512-thread blocks, tile 16 s x 128 o x 64 b.
// 8 waves: wave wid -> o-half (wid&1)*64, b-quarter (wid>>1)*16. Per-wave
// structure identical to round 10 (afrag[4], addf[4], 16 b-iters); only the
// wave->tile mapping changes. Grid 512 = 8 XCD x 64; swizzle
// lb=(phys&7)*64+(phys>>3): XCD k owns s-chunks [8k,8k+8) x all 8 o-blocks
// -> disjoint xq slice per XCD. Row-assembly: per block a row gets 512 B
// (2 o-half waves), only 4 blocks co-assemble each 4 KB row (vs 16 in r10).
// Occupancy: 2 blocks/CU x 8 waves = 16 waves/CU — same as round 10.
// ---------------------------------------------------------------------------
__global__ __launch_bounds__(512) void bitgemm(
    const unsigned short* __restrict__ xq,       // [65536][32] bf16 int
    const float*          __restrict__ rxs,      // [65536] am/127
    const float*          __restrict__ W,        // [1024][32] f32
    const float*          __restrict__ partial,  // [8]
    const float*          __restrict__ bias,     // [1024]
    float* __restrict__ out)                     // [65536][1024]
{
    const int lane = threadIdx.x & 63;
    const int wid  = threadIdx.x >> 6;        // 0..7
    const int l15  = lane & 15;
    const int hi   = lane >> 4;               // 0..3

    // XCD-aware swizzle (bijective: 512 = 8 XCDs x 64)
    const int lb   = (blockIdx.x & 7) * 64 + (blockIdx.x >> 3);
    const int oblk = lb & 7;                  // 8 o-blocks of 128
    const int sblk = lb >> 3;                 // 64 s-chunks
    const int o0   = oblk * 128 + (wid & 1) * 64;   // wave's o-base
    const int s0   = sblk * 16;
    const int bq   = wid >> 1;                // b-quarter 0..3

    // ---- weight scale from partials (uniform scalar path) ----
    float tot = 0.f;
    #pragma unroll
    for (int p = 0; p < 8; ++p) tot += partial[p];
    const float rw = fmaxf(tot * (1.0f / 32768.0f), 1e-5f);   // 1/scale_w
    const float sc = 1.0f / rw;                               // scale_w

    // ---- A fragments: inline ternary quant of W (once per wave) ----
    bf16x8 afrag[4];
    #pragma unroll
    for (int f = 0; f < 4; ++f) {
        const float* wr = W + (size_t)(o0 + f * 16 + l15) * KDIM + hi * 8;
        float4 wa = *reinterpret_cast<const float4*>(wr);
        float4 wb = *reinterpret_cast<const float4*>(wr + 4);
        float e[8] = {wa.x, wa.y, wa.z, wa.w, wb.x, wb.y, wb.z, wb.w};
        union { bf16x8 v; unsigned short s[8]; } u;
        #pragma unroll
        for (int j = 0; j < 8; ++j)
            u.s[j] = f32_to_bf16_exact(fminf(fmaxf(rintf(e[j] * sc), -1.0f), 1.0f));
        afrag[f] = u.v;
    }

    // ---- bias + positional encoding in-register (once per block) ----
    const float C  = -0.012976281620653759f;  // -log2(10000)/1024
    const float sf = (float)(s0 + l15);
    f32x4 addf[4];
    #pragma unroll
    for (int f = 0; f < 4; ++f) {
        const int oe = o0 + f * 16 + hi * 4;              // multiple of 4
        f32x4 bv = *reinterpret_cast<const f32x4*>(bias + oe);
        float a0 = sf * exp2f(C * (float)oe);
        float a1 = sf * exp2f(C * (float)(oe + 2));
        addf[f][0] = bv[0] + sinf(a0);
        addf[f][1] = bv[1] + cosf(a0);
        addf[f][2] = bv[2] + sinf(a1);
        addf[f][3] = bv[3] + cosf(a1);
    }

    // ---- b-loop: 16 iterations, 2x unrolled (8 stores / 2 loads in flight) ----
    #pragma unroll 2
    for (int i = 0; i < 16; ++i) {
        const int b   = bq * 16 + i;
        const int tok = (b << 10) + s0 + l15;

        bf16x8 bfrag = *reinterpret_cast<const bf16x8*>(
            xq + ((size_t)tok << 5) + hi * 8);
        const float rxw = rxs[tok] * rw;

        float* op = out + ((size_t)tok << 10) + o0 + hi * 4;
        #pragma unroll
        for (int f = 0; f < 4; ++f) {
            f32x4 acc = (f32x4){0.f, 0.f, 0.f, 0.f};
            acc = __builtin_amdgcn_mfma_f32_16x16x32_bf16(afrag[f], bfrag, acc, 0, 0, 0);
            f32x4 r;
            #pragma unroll
            for (int j = 0; j < 4; ++j)
                r[j] = fmaf(acc[j], rxw, addf[f][j]);
            *reinterpret_cast<f32x4*>(op + f * 16) = r;
        }
    }
}

// ---------------------------------------------------------------------------
extern "C" void kernel_launch(void* const* d_in, const int* in_sizes, int n_in,
                              void* d_out, int out_size, void* d_ws, size_t ws_size,
                              hipStream_t stream) {
    const float* x = (const float*)d_in[0];   // [64][1024][32]
    const float* W = (const float*)d_in[1];   // [1024][32]
    const float* b = (const float*)d_in[2];   // [1024]
    float* out = (float*)d_out;

    // ws: partial f32[8] @0 | rxs f32[65536] @256B | xq bf16[65536][32] @512KB
    char* wsb = (char*)d_ws;
    float*          partial = (float*)wsb;
    float*          rxs     = (float*)(wsb + 256);
    unsigned short* xq      = (unsigned short*)(wsb + (512u << 10));

    prep_kernel<<<NWP + NQX, 256, 0, stream>>>(x, W, partial, xq, rxs);
    bitgemm<<<512, 512, 0, stream>>>(xq, rxs, W, partial, b, out);
}

// Round 12
// 56.487 us; speedup vs baseline: 3.1331x; 1.0011x over previous
//
#include <hip/hip_runtime.h>
#include <cstdint>
#include <cstddef>

// x[64][1024][32] f32, W[1024][32] f32, b[1024] f32 -> out[64][1024][1024] f32
#define BATCH   64
#define SEQLEN  1024
#define KDIM    32
#define ODIM    1024
#define NTOK    (BATCH * SEQLEN)

#define NWP 8        // wpartial blocks
#define NQX 1024     // quant_x blocks (65536*32 / 8 elems-per-thread / 256)

typedef __attribute__((ext_vector_type(8))) short bf16x8;   // 8 bf16 = 4 VGPRs
typedef __attribute__((ext_vector_type(4))) float f32x4;

// exact f32 -> bf16 truncation; exact for integer-valued f32 |v| <= 255 and {-1,0,1}
__device__ __forceinline__ unsigned short f32_to_bf16_exact(float f) {
    union { float f; unsigned int u; } cv; cv.f = f;
    return (unsigned short)(cv.u >> 16);
}

// ---------------------------------------------------------------------------
// Kernel 1: merged prep — two independent jobs dispatched by block range.
//   blocks [0,8):        W |.| partial sums (deterministic tree reduce)
//   blocks [8, 8+1024):  activation quant x8-vectorized -> xq int bf16,
//                        rxs = clip(absmax,1e-5)/127
// ---------------------------------------------------------------------------
__global__ __launch_bounds__(256) void prep_kernel(const float* __restrict__ x,
                                                   const float* __restrict__ W,
                                                   float* __restrict__ partial,
                                                   unsigned short* __restrict__ xq,
                                                   float* __restrict__ rxs) {
    const int blk = blockIdx.x;
    const int t   = threadIdx.x;

    if (blk < NWP) {
        // ---- W |.| partial sums: 8 blocks x 256 threads x 16 elems ----
        __shared__ float red[256];
        const float4* W4 = reinterpret_cast<const float4*>(W) + (size_t)blk * 1024 + t * 4;
        float acc = 0.f;
        #pragma unroll
        for (int j = 0; j < 4; ++j) {
            float4 v = W4[j];
            acc += fabsf(v.x) + fabsf(v.y) + fabsf(v.z) + fabsf(v.w);
        }
        red[t] = acc;
        __syncthreads();
        for (int step = 128; step > 0; step >>= 1) {
            if (t < step) red[t] += red[t + step];
            __syncthreads();
        }
        if (t == 0) partial[blk] = red[0];
    } else {
        // ---- activation quant: thread owns 8 elems; 4 threads = 1 token ----
        const int g = (blk - NWP) * 256 + t;         // 8-elem group index
        const float* xg = x + ((size_t)g << 3);
        float4 xa = *reinterpret_cast<const float4*>(xg);
        float4 xb = *reinterpret_cast<const float4*>(xg + 4);
        float a = fmaxf(fmaxf(fmaxf(fabsf(xa.x), fabsf(xa.y)),
                              fmaxf(fabsf(xa.z), fabsf(xa.w))),
                        fmaxf(fmaxf(fabsf(xb.x), fabsf(xb.y)),
                              fmaxf(fabsf(xb.z), fabsf(xb.w))));
        a = fmaxf(a, __shfl_xor(a, 1, 4));           // 4-lane token group
        a = fmaxf(a, __shfl_xor(a, 2, 4));
        const float am = fmaxf(a, 1e-5f);
        const float scale = 127.0f / am;             // |v*scale|<=127: clip can't bind
        float e[8] = {xa.x, xa.y, xa.z, xa.w, xb.x, xb.y, xb.z, xb.w};
        union { bf16x8 v; unsigned short s[8]; } u;
        #pragma unroll
        for (int j = 0; j < 8; ++j)
            u.s[j] = f32_to_bf16_exact(rintf(e[j] * scale));   // int, exact bf16
        *reinterpret_cast<bf16x8*>(xq + ((size_t)g << 3)) = u.v;
        if ((g & 3) == 0) rxs[g >> 2] = am * (1.0f / 127.0f);
    }
}

// ---------------------------------------------------------------------------
// Kernel 2: BitLinear GEMM — 512-thread blocks, tile 16 s x 256 o x 32 b.
// 8 waves: wave wid -> o-quarter (wid&3)*64, b-octet (wid>>2)*16 within the
// block's 32-b half. Per-wave structure identical to r10/r11 (afrag[4],
// addf[4], 16 b-iters, unroll 2). Grid 512 = 64 s x 4 o x 2 bh = 8 XCD x 64;
// swizzle: XCD k owns s-chunks [8k,8k+8) -> disjoint xq slice; all 4 blocks
// co-assembling an output row share (s-chunk,bhalf) -> same XCD's L2.
// Row-assembly: per block a row gets 1 KB (4 o-quarter waves), only 4 blocks
// per 4 KB row (vs 8 in r11). Occupancy: 2 blocks/CU x 8 waves = 16 waves/CU
// — same as r11 (controlled).
// ---------------------------------------------------------------------------
__global__ __launch_bounds__(512) void bitgemm(
    const unsigned short* __restrict__ xq,       // [65536][32] bf16 int
    const float*          __restrict__ rxs,      // [65536] am/127
    const float*          __restrict__ W,        // [1024][32] f32
    const float*          __restrict__ partial,  // [8]
    const float*          __restrict__ bias,     // [1024]
    float* __restrict__ out)                     // [65536][1024]
{
    const int lane = threadIdx.x & 63;
    const int wid  = threadIdx.x >> 6;        // 0..7
    const int l15  = lane & 15;
    const int hi   = lane >> 4;               // 0..3

    // XCD-aware swizzle (bijective: 512 = 8 XCDs x 64)
    const int lb    = (blockIdx.x & 7) * 64 + (blockIdx.x >> 3);
    const int sblk  = lb >> 3;                // 64 s-chunks (8 per XCD)
    const int oblk  = lb & 3;                 // 4 o-blocks of 256
    const int bhalf = (lb >> 2) & 1;          // 2 b-halves of 32
    const int o0    = oblk * 256 + (wid & 3) * 64;   // wave's o-base
    const int s0    = sblk * 16;
    const int bq    = bhalf * 2 + (wid >> 2); // wave's b-octet 0..3 (16 b each)

    // ---- weight scale from partials (uniform scalar path) ----
    float tot = 0.f;
    #pragma unroll
    for (int p = 0; p < 8; ++p) tot += partial[p];
    const float rw = fmaxf(tot * (1.0f / 32768.0f), 1e-5f);   // 1/scale_w
    const float sc = 1.0f / rw;                               // scale_w

    // ---- A fragments: inline ternary quant of W (once per wave) ----
    bf16x8 afrag[4];
    #pragma unroll
    for (int f = 0; f < 4; ++f) {
        const float* wr = W + (size_t)(o0 + f * 16 + l15) * KDIM + hi * 8;
        float4 wa = *reinterpret_cast<const float4*>(wr);
        float4 wb = *reinterpret_cast<const float4*>(wr + 4);
        float e[8] = {wa.x, wa.y, wa.z, wa.w, wb.x, wb.y, wb.z, wb.w};
        union { bf16x8 v; unsigned short s[8]; } u;
        #pragma unroll
        for (int j = 0; j < 8; ++j)
            u.s[j] = f32_to_bf16_exact(fminf(fmaxf(rintf(e[j] * sc), -1.0f), 1.0f));
        afrag[f] = u.v;
    }

    // ---- bias + positional encoding in-register (once per block) ----
    const float C  = -0.012976281620653759f;  // -log2(10000)/1024
    const float sf = (float)(s0 + l15);
    f32x4 addf[4];
    #pragma unroll
    for (int f = 0; f < 4; ++f) {
        const int oe = o0 + f * 16 + hi * 4;              // multiple of 4
        f32x4 bv = *reinterpret_cast<const f32x4*>(bias + oe);
        float a0 = sf * exp2f(C * (float)oe);
        float a1 = sf * exp2f(C * (float)(oe + 2));
        addf[f][0] = bv[0] + sinf(a0);
        addf[f][1] = bv[1] + cosf(a0);
        addf[f][2] = bv[2] + sinf(a1);
        addf[f][3] = bv[3] + cosf(a1);
    }

    // ---- b-loop: 16 iterations, 2x unrolled (8 stores / 2 loads in flight) ----
    #pragma unroll 2
    for (int i = 0; i < 16; ++i) {
        const int b   = bq * 16 + i;
        const int tok = (b << 10) + s0 + l15;

        bf16x8 bfrag = *reinterpret_cast<const bf16x8*>(
            xq + ((size_t)tok << 5) + hi * 8);
        const float rxw = rxs[tok] * rw;

        float* op = out + ((size_t)tok << 10) + o0 + hi * 4;
        #pragma unroll
        for (int f = 0; f < 4; ++f) {
            f32x4 acc = (f32x4){0.f, 0.f, 0.f, 0.f};
            acc = __builtin_amdgcn_mfma_f32_16x16x32_bf16(afrag[f], bfrag, acc, 0, 0, 0);
            f32x4 r;
            #pragma unroll
            for (int j = 0; j < 4; ++j)
                r[j] = fmaf(acc[j], rxw, addf[f][j]);
            *reinterpret_cast<f32x4*>(op + f * 16) = r;
        }
    }
}

// ---------------------------------------------------------------------------
extern "C" void kernel_launch(void* const* d_in, const int* in_sizes, int n_in,
                              void* d_out, int out_size, void* d_ws, size_t ws_size,
                              hipStream_t stream) {
    const float* x = (const float*)d_in[0];   // [64][1024][32]
    const float* W = (const float*)d_in[1];   // [1024][32]
    const float* b = (const float*)d_in[2];   // [1024]
    float* out = (float*)d_out;

    // ws: partial f32[8] @0 | rxs f32[65536] @256B | xq bf16[65536][32] @512KB
    char* wsb = (char*)d_ws;
    float*          partial = (float*)wsb;
    float*          rxs     = (float*)(wsb + 256);
    unsigned short* xq      = (unsigned short*)(wsb + (512u << 10));

    prep_kernel<<<NWP + NQX, 256, 0, stream>>>(x, W, partial, xq, rxs);
    bitgemm<<<512, 512, 0, stream>>>(xq, rxs, W, partial, b, out);
}